// Round 13
// baseline (130.799 us; speedup 1.0000x reference)
//
#include <hip/hip_runtime.h>

#define NCLS 20
#define HW   (512 * 512)
#define TPB  256
#define PPT  4           // pixels per thread (dwordx4 loads) — R11-proven, no spill

// d_ws layout: [0..2KB) per-batch acc (stride 64 uints):
//   [0] float lseg_sum  [1] float fcl_sum
//   [2..21] cnt_tgt[c]  [22..41] cnt_pred[c]  [42..61] tp[c]
// acc[nb*64] = done-block counter.  [4096 ..) u8 label map [B][HW]
#define ACC_STRIDE 64

typedef float v4f __attribute__((ext_vector_type(4)));

// ---------- kernel 1: label extraction + acc zeroing ----------
// NT loads: tgt is single-use; don't evict the L3-resident pred between
// graph replays (R10: -7.4us). Block 0 zeroes acc+counter (kills the memset
// dispatch; next-kernel visibility is the standard stream release/acquire).
__global__ __launch_bounds__(256) void seg_label(
    const float* __restrict__ tgt, unsigned char* __restrict__ lab,
    unsigned* __restrict__ acc, unsigned accw, unsigned nf4)
{
    if (blockIdx.x == 0) {
        for (unsigned i = threadIdx.x; i <= accw; i += 256u) acc[i] = 0u;
    }
    const unsigned NTHR = 4096u * 256u;
    for (unsigned e4 = blockIdx.x * 256u + threadIdx.x; e4 < nf4; e4 += NTHR) {
        const v4f v = __builtin_nontemporal_load(
            reinterpret_cast<const v4f*>(tgt) + e4);
        const unsigned f   = e4 * 4u;              // flat float index
        const unsigned c   = (f >> 18) % NCLS;     // (f / HW) % 20
        const unsigned bb  = f / (NCLS * HW);      // batch
        const unsigned pix = f & (HW - 1);
        unsigned char* lp = lab + (size_t)bb * HW + pix;
        if (v.x > 0.5f) lp[0] = (unsigned char)c;
        if (v.y > 0.5f) lp[1] = (unsigned char)c;
        if (v.z > 0.5f) lp[2] = (unsigned char)c;
        if (v.w > 0.5f) lp[3] = (unsigned char)c;
    }
}

// ---------- kernel 2: pred gather + series BCE/focal/hist + finalize ----------
__global__ __launch_bounds__(TPB, 5) void seg_main(
    const float* __restrict__ pred,
    const unsigned char* __restrict__ lab,
    unsigned* __restrict__ acc,
    float* __restrict__ out, int nb)
{
    __shared__ unsigned h_tgt[NCLS], h_pred[NCLS], h_tp[NCLS];
    __shared__ float red[8];
    __shared__ unsigned isLast;

    const int tid = threadIdx.x;
    if (tid < NCLS) { h_tgt[tid] = 0u; h_pred[tid] = 0u; h_tp[tid] = 0u; }
    __syncthreads();

    const int b = blockIdx.y;
    const size_t pix = ((size_t)blockIdx.x * TPB + tid) * PPT;

    // saddr-form addressing (R11): one per-lane 32-bit offset + SGPR bases.
    const unsigned voff = (unsigned)(pix * 4u);          // byte off in plane
    const unsigned long long pbase =
        (unsigned long long)(uintptr_t)pred + (unsigned long long)b * (NCLS * HW * 4ull);
#define SB(c) const unsigned long long sb##c = pbase + (unsigned long long)(c) * (HW * 4ull);
    SB(0) SB(1) SB(2) SB(3) SB(4) SB(5) SB(6) SB(7) SB(8) SB(9)
    SB(10) SB(11) SB(12) SB(13) SB(14) SB(15) SB(16) SB(17) SB(18) SB(19)
    const unsigned long long sbl =
        (unsigned long long)(uintptr_t)lab + (unsigned long long)b * HW;
    const unsigned voffl = (unsigned)pix;

    // Per-pixel state (named scalars): M1..M3 power sums, max+argmax, xlab.
#define DECLPX(P) \
    float M1_##P = 0.0f, M2_##P = 0.0f, M3_##P = 0.0f, \
          mx_##P = -1e30f, xl_##P = 0.0f; \
    int pa_##P = 0;
    DECLPX(0) DECLPX(1) DECLPX(2) DECLPX(3)

    v4f xv0, xv1, xv2, xv3, xv4, xv5, xv6, xv7, xv8, xv9,
        xv10, xv11, xv12, xv13, xv14, xv15, xv16, xv17, xv18, xv19;
    unsigned labu;

    // asm-issued loads (vaddr+saddr): issue order pinned (R11-proven).
#define ISSUE4(c0, c1, c2, c3)                                              \
    asm volatile(                                                           \
        "global_load_dwordx4 %0, %4, %5\n\t"                                \
        "global_load_dwordx4 %1, %4, %6\n\t"                                \
        "global_load_dwordx4 %2, %4, %7\n\t"                                \
        "global_load_dwordx4 %3, %4, %8"                                    \
        : "=&v"(xv##c0), "=&v"(xv##c1), "=&v"(xv##c2), "=&v"(xv##c3)        \
        : "v"(voff), "s"(sb##c0), "s"(sb##c1), "s"(sb##c2), "s"(sb##c3))

#define WAITV(N)                                              \
    asm volatile("s_waitcnt vmcnt(" #N ")" ::: "memory");     \
    __builtin_amdgcn_sched_barrier(0)

    // Per element: exp, 3 power-sum updates, argmax, label-logit select.
#define PROC1(c, X, P) {                                                    \
    const float x_ = (X);                                                   \
    const float e_ = __expf(x_);                                            \
    const float e2_ = e_ * e_;                                              \
    M1_##P += e_;                                                           \
    M2_##P += e2_;                                                          \
    M3_##P = __builtin_fmaf(e2_, e_, M3_##P);                               \
    const bool b_ = x_ > mx_##P;                                            \
    mx_##P = b_ ? x_ : mx_##P;  pa_##P = b_ ? (c) : pa_##P;                 \
    xl_##P = ((c) == lb##P) ? x_ : xl_##P; }

#define PROCC(c) PROC1(c, xv##c.x, 0) PROC1(c, xv##c.y, 1) \
                 PROC1(c, xv##c.z, 2) PROC1(c, xv##c.w, 3)
#define PROC4(c0, c1, c2, c3) PROCC(c0) PROCC(c1) PROCC(c2) PROCC(c3)

    // Pipeline: label + 12 pred loads in flight (R11 schedule, verbatim).
    asm volatile("global_load_dword %0, %1, %2"
                 : "=&v"(labu) : "v"(voffl), "s"(sbl));
    ISSUE4(0, 1, 2, 3);
    ISSUE4(4, 5, 6, 7);
    ISSUE4(8, 9, 10, 11);
    WAITV(12);                       // label byte ready
    const int lb0 = (int)(labu & 0xffu);
    const int lb1 = (int)((labu >> 8) & 0xffu);
    const int lb2 = (int)((labu >> 16) & 0xffu);
    const int lb3 = (int)(labu >> 24);
    WAITV(8);   PROC4(0, 1, 2, 3);   ISSUE4(12, 13, 14, 15);
    WAITV(8);   PROC4(4, 5, 6, 7);   ISSUE4(16, 17, 18, 19);
    WAITV(8);   PROC4(8, 9, 10, 11);
    WAITV(4);   PROC4(12, 13, 14, 15);
    WAITV(0);   PROC4(16, 17, 18, 19);

    // Epilogue per pixel:
    //   Sum_all -log(1-p_c) ~= T3 + Rpa; T3 = series k<=3 over all c,
    //   Rpa = exact k>=4 tail of the max channel (the only slow one)
    //       = -log(1-ppa) - ppa - ppa^2/2 - ppa^3/3.
    //   lseg_pix = T3 + Rpa + log(1-p_lab) - (xl - logS)
    //   focal    = -(xl - logS) * (1-p_lab)^2
    float tl = 0.0f, tf = 0.0f;
#define FINPX(P) {                                                          \
    const float S_ = M1_##P, is_ = 1.0f / S_, is2_ = is_ * is_;             \
    const float logS_ = __logf(S_);                                         \
    const float T3_ = 1.0f + 0.5f * M2_##P * is2_                           \
                    + 0.33333333f * M3_##P * is2_ * is_;                    \
    const float ppa_ = __expf(mx_##P) * is_;                                \
    const float Rpa_ = -__logf(fmaxf(1.0f - ppa_, 1e-12f)) - ppa_           \
                     - 0.5f * ppa_ * ppa_                                   \
                     - 0.33333333f * ppa_ * ppa_ * ppa_;                    \
    const float loglab_ = xl_##P - logS_;                                   \
    const float plab_ = __expf(xl_##P) * is_;                               \
    const float l1m_ = __logf(fmaxf(1.0f - plab_, 1e-37f));                 \
    tl += T3_ + Rpa_ + l1m_ - loglab_;                                      \
    const float om_ = 1.0f - plab_;                                         \
    tf -= loglab_ * om_ * om_;                                              \
    atomicAdd(&h_tgt[lb##P], 1u);                                           \
    atomicAdd(&h_pred[pa_##P], 1u);                                         \
    if (pa_##P == lb##P) atomicAdd(&h_tp[lb##P], 1u); }

    FINPX(0) FINPX(1) FINPX(2) FINPX(3)

    // ---- reduce float sums: wave shuffle, then cross-wave via LDS ----
#pragma unroll
    for (int off = 32; off > 0; off >>= 1) {
        tl += __shfl_down(tl, off, 64);
        tf += __shfl_down(tf, off, 64);
    }
    const int wid = tid >> 6, lane = tid & 63;
    if (lane == 0) { red[wid] = tl; red[4 + wid] = tf; }
    __syncthreads();   // also makes h_* histogram atomics visible

    unsigned* ab = acc + (size_t)b * ACC_STRIDE;
    if (tid == 0) {
        const float a = red[0] + red[1] + red[2] + red[3];
        const float f = red[4] + red[5] + red[6] + red[7];
        atomicAdd(reinterpret_cast<float*>(ab + 0), a);
        atomicAdd(reinterpret_cast<float*>(ab + 1), f);
    }
    if (tid < NCLS) {
        atomicAdd(&ab[2  + tid], h_tgt[tid]);
        atomicAdd(&ab[22 + tid], h_pred[tid]);
        atomicAdd(&ab[42 + tid], h_tp[tid]);
    }

    // ---- last-block finalize (replaces seg_final dispatch) ----
    __syncthreads();   // waves drain vmcnt at barrier -> block's atomics done
    if (tid == 0) {
        __threadfence();
        const unsigned done = atomicAdd(&acc[(size_t)nb * ACC_STRIDE], 1u);
        isLast = (done == gridDim.x * gridDim.y - 1u) ? 1u : 0u;
    }
    __syncthreads();
    if (isLast) {
        // Read acc via device-scope ATOMIC reads: plain loads could hit a
        // stale per-XCD L2 line (Guideline 16); atomics go to the coherence
        // point where all writers' atomics executed.
        const int fb = tid >> 5, fc = tid & 31;
        float iou_c = 0.0f, pres = 0.0f;
        if (fb < nb && fc < NCLS) {
            unsigned* fab = acc + (size_t)fb * ACC_STRIDE;
            unsigned tg  = atomicOr(&fab[2  + fc], 0u);
            unsigned pd  = atomicOr(&fab[22 + fc], 0u);
            unsigned tpv = atomicOr(&fab[42 + fc], 0u);
            unsigned denom = tg + pd - tpv;          // tp + fp + fn
            if (tg > 0) pres = 1.0f;
            if (denom > 0) iou_c = (float)tpv / (float)denom;
        }
#pragma unroll
        for (int off = 16; off > 0; off >>= 1) {
            iou_c += __shfl_down(iou_c, off, 32);
            pres  += __shfl_down(pres,  off, 32);
        }
        if (fc == 0 && fb < nb) {
            unsigned* fab = acc + (size_t)fb * ACC_STRIDE;
            float s0 = atomicAdd(reinterpret_cast<float*>(fab + 0), 0.0f);
            float s1 = atomicAdd(reinterpret_cast<float*>(fab + 1), 0.0f);
            float lseg = s0 * (1.0f / ((float)NCLS * (float)HW));
            float fcl  = s1 * (1.0f / (float)HW);
            float iou  = (pres > 0.0f) ? (iou_c / pres) : 0.0f;
            red[fb] = lseg + (1.0f - iou) + fcl;
        }
        __syncthreads();
        if (tid == 0) {
            float t = 0.0f;
            for (int i = 0; i < nb; ++i) t += red[i];
            out[0] = t / (float)nb;
        }
    }
}

extern "C" void kernel_launch(void* const* d_in, const int* in_sizes, int n_in,
                              void* d_out, int out_size, void* d_ws, size_t ws_size,
                              hipStream_t stream)
{
    const float* pred = (const float*)d_in[0];
    const float* tgt  = (const float*)d_in[1];
    float* out = (float*)d_out;
    unsigned* acc = (unsigned*)d_ws;
    unsigned char* labels = (unsigned char*)d_ws + 4096;

    const int nb = in_sizes[0] / (NCLS * HW);   // batch = 8
    const unsigned nf4 = (unsigned)(in_sizes[1] / 4);

    seg_label<<<4096, 256, 0, stream>>>(tgt, labels, acc,
                                        (unsigned)(nb * ACC_STRIDE), nf4);

    dim3 grid(HW / (TPB * PPT), nb);            // (256, 8)
    seg_main<<<grid, TPB, 0, stream>>>(pred, labels, acc, out, nb);
}

// Round 14
// 82.812 us; speedup vs baseline: 1.5795x; 1.5795x over previous
//
#include <hip/hip_runtime.h>

#define NCLS 20
#define HW   (512 * 512)
#define TPB  256
#define PPT  4           // pixels per thread (dwordx4 loads) — proven no-spill

// d_ws layout: [0..2KB) per-batch acc (stride 64 uints):
//   [0] float lseg_sum  [1] float fcl_sum
//   [2..21] cnt_tgt[c]  [22..41] cnt_pred[c]  [42..61] tp[c]
// [4096 ..) u8 label map [B][HW]
#define ACC_STRIDE 64

typedef float v4f __attribute__((ext_vector_type(4)));

// ---------- kernel 1: label extraction — pure linear stream ----------
// NT loads: tgt is single-use; don't evict the L3-resident pred between
// graph replays (R10: -7.4us proven). One byte store per pixel (one-hot).
__global__ __launch_bounds__(256) void seg_label(
    const float* __restrict__ tgt, unsigned char* __restrict__ lab,
    unsigned nf4)
{
    const unsigned NTHR = 4096u * 256u;
    for (unsigned e4 = blockIdx.x * 256u + threadIdx.x; e4 < nf4; e4 += NTHR) {
        const v4f v = __builtin_nontemporal_load(
            reinterpret_cast<const v4f*>(tgt) + e4);
        const unsigned f   = e4 * 4u;              // flat float index
        const unsigned c   = (f >> 18) % NCLS;     // (f / HW) % 20
        const unsigned bb  = f / (NCLS * HW);      // batch
        const unsigned pix = f & (HW - 1);
        unsigned char* lp = lab + (size_t)bb * HW + pix;
        if (v.x > 0.5f) lp[0] = (unsigned char)c;
        if (v.y > 0.5f) lp[1] = (unsigned char)c;
        if (v.z > 0.5f) lp[2] = (unsigned char)c;
        if (v.w > 0.5f) lp[3] = (unsigned char)c;
    }
}

// ---------- kernel 2: pred gather + series BCE/focal/hist ----------
// NO device-scope fences here (R13: per-block __threadfence -> L2
// writeback/invalidate storm, 3x slowdown). Finalize is a separate dispatch.
__global__ __launch_bounds__(TPB, 5) void seg_main(
    const float* __restrict__ pred,
    const unsigned char* __restrict__ lab,
    unsigned* __restrict__ acc)
{
    __shared__ unsigned h_tgt[NCLS], h_pred[NCLS], h_tp[NCLS];
    __shared__ float red[8];

    const int tid = threadIdx.x;
    if (tid < NCLS) { h_tgt[tid] = 0u; h_pred[tid] = 0u; h_tp[tid] = 0u; }
    __syncthreads();

    const int b = blockIdx.y;
    const size_t pix = ((size_t)blockIdx.x * TPB + tid) * PPT;

    // saddr-form addressing (R11): one per-lane 32-bit offset + SGPR bases.
    const unsigned voff = (unsigned)(pix * 4u);          // byte off in plane
    const unsigned long long pbase =
        (unsigned long long)(uintptr_t)pred + (unsigned long long)b * (NCLS * HW * 4ull);
#define SB(c) const unsigned long long sb##c = pbase + (unsigned long long)(c) * (HW * 4ull);
    SB(0) SB(1) SB(2) SB(3) SB(4) SB(5) SB(6) SB(7) SB(8) SB(9)
    SB(10) SB(11) SB(12) SB(13) SB(14) SB(15) SB(16) SB(17) SB(18) SB(19)
    const unsigned long long sbl =
        (unsigned long long)(uintptr_t)lab + (unsigned long long)b * HW;
    const unsigned voffl = (unsigned)pix;

    // Per-pixel state (named scalars): M1..M3 power sums, max+argmax, xlab.
#define DECLPX(P) \
    float M1_##P = 0.0f, M2_##P = 0.0f, M3_##P = 0.0f, \
          mx_##P = -1e30f, xl_##P = 0.0f; \
    int pa_##P = 0;
    DECLPX(0) DECLPX(1) DECLPX(2) DECLPX(3)

    v4f xv0, xv1, xv2, xv3, xv4, xv5, xv6, xv7, xv8, xv9,
        xv10, xv11, xv12, xv13, xv14, xv15, xv16, xv17, xv18, xv19;
    unsigned labu;

    // asm-issued loads (vaddr+saddr): issue order pinned (R11-proven).
#define ISSUE4(c0, c1, c2, c3)                                              \
    asm volatile(                                                           \
        "global_load_dwordx4 %0, %4, %5\n\t"                                \
        "global_load_dwordx4 %1, %4, %6\n\t"                                \
        "global_load_dwordx4 %2, %4, %7\n\t"                                \
        "global_load_dwordx4 %3, %4, %8"                                    \
        : "=&v"(xv##c0), "=&v"(xv##c1), "=&v"(xv##c2), "=&v"(xv##c3)        \
        : "v"(voff), "s"(sb##c0), "s"(sb##c1), "s"(sb##c2), "s"(sb##c3))

#define WAITV(N)                                              \
    asm volatile("s_waitcnt vmcnt(" #N ")" ::: "memory");     \
    __builtin_amdgcn_sched_barrier(0)

    // Per element: exp, 3 power-sum updates, argmax, label-logit select.
#define PROC1(c, X, P) {                                                    \
    const float x_ = (X);                                                   \
    const float e_ = __expf(x_);                                            \
    const float e2_ = e_ * e_;                                              \
    M1_##P += e_;                                                           \
    M2_##P += e2_;                                                          \
    M3_##P = __builtin_fmaf(e2_, e_, M3_##P);                               \
    const bool b_ = x_ > mx_##P;                                            \
    mx_##P = b_ ? x_ : mx_##P;  pa_##P = b_ ? (c) : pa_##P;                 \
    xl_##P = ((c) == lb##P) ? x_ : xl_##P; }

#define PROCC(c) PROC1(c, xv##c.x, 0) PROC1(c, xv##c.y, 1) \
                 PROC1(c, xv##c.z, 2) PROC1(c, xv##c.w, 3)
#define PROC4(c0, c1, c2, c3) PROCC(c0) PROCC(c1) PROCC(c2) PROCC(c3)

    // Pipeline: label + 12 pred loads in flight (R11 schedule, verbatim).
    asm volatile("global_load_dword %0, %1, %2"
                 : "=&v"(labu) : "v"(voffl), "s"(sbl));
    ISSUE4(0, 1, 2, 3);
    ISSUE4(4, 5, 6, 7);
    ISSUE4(8, 9, 10, 11);
    WAITV(12);                       // label byte ready
    const int lb0 = (int)(labu & 0xffu);
    const int lb1 = (int)((labu >> 8) & 0xffu);
    const int lb2 = (int)((labu >> 16) & 0xffu);
    const int lb3 = (int)(labu >> 24);
    WAITV(8);   PROC4(0, 1, 2, 3);   ISSUE4(12, 13, 14, 15);
    WAITV(8);   PROC4(4, 5, 6, 7);   ISSUE4(16, 17, 18, 19);
    WAITV(8);   PROC4(8, 9, 10, 11);
    WAITV(4);   PROC4(12, 13, 14, 15);
    WAITV(0);   PROC4(16, 17, 18, 19);

    // Epilogue per pixel (validated numerically in R13, absmax 0.0):
    //   Sum_all -log(1-p_c) ~= T3 + Rpa; T3 = series k<=3 over all c,
    //   Rpa = exact k>=4 tail of the max channel
    //       = -log(1-ppa) - ppa - ppa^2/2 - ppa^3/3.
    //   lseg_pix = T3 + Rpa + log(1-p_lab) - (xl - logS)
    //   focal    = -(xl - logS) * (1-p_lab)^2
    float tl = 0.0f, tf = 0.0f;
#define FINPX(P) {                                                          \
    const float S_ = M1_##P, is_ = 1.0f / S_, is2_ = is_ * is_;             \
    const float logS_ = __logf(S_);                                         \
    const float T3_ = 1.0f + 0.5f * M2_##P * is2_                           \
                    + 0.33333333f * M3_##P * is2_ * is_;                    \
    const float ppa_ = __expf(mx_##P) * is_;                                \
    const float Rpa_ = -__logf(fmaxf(1.0f - ppa_, 1e-12f)) - ppa_           \
                     - 0.5f * ppa_ * ppa_                                   \
                     - 0.33333333f * ppa_ * ppa_ * ppa_;                    \
    const float loglab_ = xl_##P - logS_;                                   \
    const float plab_ = __expf(xl_##P) * is_;                               \
    const float l1m_ = __logf(fmaxf(1.0f - plab_, 1e-37f));                 \
    tl += T3_ + Rpa_ + l1m_ - loglab_;                                      \
    const float om_ = 1.0f - plab_;                                         \
    tf -= loglab_ * om_ * om_;                                              \
    atomicAdd(&h_tgt[lb##P], 1u);                                           \
    atomicAdd(&h_pred[pa_##P], 1u);                                         \
    if (pa_##P == lb##P) atomicAdd(&h_tp[lb##P], 1u); }

    FINPX(0) FINPX(1) FINPX(2) FINPX(3)

    // ---- reduce float sums: wave shuffle, then cross-wave via LDS ----
#pragma unroll
    for (int off = 32; off > 0; off >>= 1) {
        tl += __shfl_down(tl, off, 64);
        tf += __shfl_down(tf, off, 64);
    }
    const int wid = tid >> 6, lane = tid & 63;
    if (lane == 0) { red[wid] = tl; red[4 + wid] = tf; }
    __syncthreads();   // also makes h_* histogram atomics visible

    unsigned* ab = acc + (size_t)b * ACC_STRIDE;
    if (tid == 0) {
        const float a = red[0] + red[1] + red[2] + red[3];
        const float f = red[4] + red[5] + red[6] + red[7];
        atomicAdd(reinterpret_cast<float*>(ab + 0), a);
        atomicAdd(reinterpret_cast<float*>(ab + 1), f);
    }
    if (tid < NCLS) {
        atomicAdd(&ab[2  + tid], h_tgt[tid]);
        atomicAdd(&ab[22 + tid], h_pred[tid]);
        atomicAdd(&ab[42 + tid], h_tp[tid]);
    }
}

__global__ __launch_bounds__(256) void seg_final(
    const unsigned* __restrict__ acc, float* __restrict__ out, int nb)
{
    __shared__ float bl[8];
    const int tid = threadIdx.x;
    const int b = tid >> 5, c = tid & 31;

    float iou_c = 0.0f, pres = 0.0f;
    if (b < nb && c < NCLS) {
        const unsigned* ab = acc + (size_t)b * ACC_STRIDE;
        unsigned tg = ab[2 + c], pd = ab[22 + c], tpv = ab[42 + c];
        unsigned denom = tg + pd - tpv;          // tp + fp + fn
        if (tg > 0) pres = 1.0f;
        if (denom > 0) iou_c = (float)tpv / (float)denom;
    }
#pragma unroll
    for (int off = 16; off > 0; off >>= 1) {
        iou_c += __shfl_down(iou_c, off, 32);
        pres  += __shfl_down(pres,  off, 32);
    }
    if (c == 0 && b < nb) {
        const unsigned* ab = acc + (size_t)b * ACC_STRIDE;
        const float*    fs = reinterpret_cast<const float*>(ab);
        float lseg = fs[0] * (1.0f / ((float)NCLS * (float)HW));
        float fcl  = fs[1] * (1.0f / (float)HW);
        float iou  = (pres > 0.0f) ? (iou_c / pres) : 0.0f;
        bl[b] = lseg + (1.0f - iou) + fcl;
    }
    __syncthreads();
    if (tid == 0) {
        float t = 0.0f;
        for (int i = 0; i < nb; ++i) t += bl[i];
        out[0] = t / (float)nb;
    }
}

extern "C" void kernel_launch(void* const* d_in, const int* in_sizes, int n_in,
                              void* d_out, int out_size, void* d_ws, size_t ws_size,
                              hipStream_t stream)
{
    const float* pred = (const float*)d_in[0];
    const float* tgt  = (const float*)d_in[1];
    float* out = (float*)d_out;
    unsigned* acc = (unsigned*)d_ws;
    unsigned char* labels = (unsigned char*)d_ws + 4096;

    const int nb = in_sizes[0] / (NCLS * HW);   // batch = 8
    const unsigned nf4 = (unsigned)(in_sizes[1] / 4);

    (void)hipMemsetAsync(acc, 0, (size_t)nb * ACC_STRIDE * sizeof(unsigned), stream);

    seg_label<<<4096, 256, 0, stream>>>(tgt, labels, nf4);

    dim3 grid(HW / (TPB * PPT), nb);            // (256, 8)
    seg_main<<<grid, TPB, 0, stream>>>(pred, labels, acc);
    seg_final<<<1, 256, 0, stream>>>(acc, out, nb);
}